// Round 2
// baseline (548.112 us; speedup 1.0000x reference)
//
#include <hip/hip_runtime.h>
#include <math.h>

// Match numpy's non-FMA evaluation of the distance formula (ranking fidelity).
#pragma clang fp contract(off)

#define NPTS 4096
#define KNN  16
#define RPB  64    // rows per block in knn kernel
#define TA   256   // threads in knn kernel (4 threads per row)

// ---------------------------------------------------------------------------
// Kernel: zero the degree accumulator (ws is poisoned 0xAA each call)
// ---------------------------------------------------------------------------
__global__ void zero_kernel(float* __restrict__ p, int n) {
    int i = blockIdx.x * blockDim.x + threadIdx.x;
    if (i < n) p[i] = 0.0f;
}

// ---------------------------------------------------------------------------
// Kernel: KNN + weights + degree accumulation.
// One block = 64 rows of one batch; 4 threads per row, each scans an
// interleaved quarter of the 4096 candidates (m = chunk + 4*i) keeping a
// sorted top-16; then exact-distance weights; then 4-way merge per row.
// Tie-break everywhere: strictly-less keeps the earlier (smaller) index,
// merge breaks exact ties by smaller index — matches lax.top_k stability.
// ---------------------------------------------------------------------------
__global__ __launch_bounds__(TA) void knn_kernel(const float* __restrict__ xyz,
                                                 float* __restrict__ Dsum,
                                                 int* __restrict__ idx_out,
                                                 float* __restrict__ w_out) {
    __shared__ float4 spts[NPTS];               // 64 KB: (x,y,z,|p|^2)
    // merge buffers alias spts after the second barrier (48 KB needed)
    float* md = (float*)spts;                   // [16][256] distances
    int*   mi = ((int*)spts) + NPTS;            // [16][256] indices
    float* mw = ((float*)spts) + 2 * NPTS;      // [16][256] weights

    const int t   = threadIdx.x;
    const int b   = blockIdx.x >> 6;            // 64 blocks per batch
    const int blk = blockIdx.x & 63;
    const float* X = xyz + (size_t)b * 3 * NPTS;

    // stage points + squared norms into LDS (numpy order: (x*x+y*y)+z*z)
    for (int i = t; i < NPTS; i += TA) {
        float x = X[i], y = X[NPTS + i], z = X[2 * NPTS + i];
        float sq = (x * x + y * y) + z * z;
        spts[i] = make_float4(x, y, z, sq);
    }
    __syncthreads();

    const int row_local = t >> 2;
    const int chunk     = t & 3;
    const int n         = blk * RPB + row_local;
    const float4 P = spts[n];

    float bestd[KNN];
    int   besti[KNN];
#pragma unroll
    for (int k = 0; k < KNN; ++k) { bestd[k] = 3.4e38f; besti[k] = 0x7fffffff; }

    for (int i = 0; i < NPTS / 4; ++i) {
        int m = chunk + (i << 2);
        float4 Q = spts[m];
        float dot = (P.x * Q.x + P.y * Q.y) + P.z * Q.z;     // numpy einsum order
        float d2  = (P.w + Q.w) - 2.0f * dot;                // (sq_n+sq_m)-2*dot
        if (d2 < bestd[KNN - 1]) {                           // strict: ties keep earlier m
            bestd[KNN - 1] = d2; besti[KNN - 1] = m;
#pragma unroll
            for (int s = KNN - 1; s > 0; --s) {
                if (bestd[s] < bestd[s - 1]) {
                    float td = bestd[s]; bestd[s] = bestd[s - 1]; bestd[s - 1] = td;
                    int   ti = besti[s]; besti[s] = besti[s - 1]; besti[s - 1] = ti;
                }
            }
        }
    }

    // exact-distance weights (reference recomputes from gathered coords)
    float lw[KNN];
#pragma unroll
    for (int k = 0; k < KNN; ++k) {
        float4 Q = spts[besti[k]];
        float dx = P.x - Q.x, dy = P.y - Q.y, dz = P.z - Q.z;
        float dist2 = (dx * dx + dy * dy) + dz * dz;
        lw[k] = expf(-0.5f * dist2);
    }
    __syncthreads();   // done with spts-as-points; reuse as merge buffer

#pragma unroll
    for (int k = 0; k < KNN; ++k) {
        md[k * TA + t] = bestd[k];
        mi[k * TA + t] = besti[k];
        mw[k * TA + t] = lw[k];
    }
    __syncthreads();

    if (chunk == 0) {
        // 4-way merge of sorted 16-lists; p0..p3 < 16 always holds while k<16
        int p0 = 0, p1 = 0, p2 = 0, p3 = 0;
        float rsum = 0.0f;
        size_t gbase = ((size_t)b * NPTS + n) * KNN;
#pragma unroll 1
        for (int k = 0; k < KNN; ++k) {
            float h0 = md[p0 * TA + t + 0]; int i0 = mi[p0 * TA + t + 0];
            float h1 = md[p1 * TA + t + 1]; int i1 = mi[p1 * TA + t + 1];
            float h2 = md[p2 * TA + t + 2]; int i2 = mi[p2 * TA + t + 2];
            float h3 = md[p3 * TA + t + 3]; int i3 = mi[p3 * TA + t + 3];
            int sel = 0; float hb = h0; int ib = i0;
            if (h1 < hb || (h1 == hb && i1 < ib)) { sel = 1; hb = h1; ib = i1; }
            if (h2 < hb || (h2 == hb && i2 < ib)) { sel = 2; hb = h2; ib = i2; }
            if (h3 < hb || (h3 == hb && i3 < ib)) { sel = 3; hb = h3; ib = i3; }
            float wsel;
            if      (sel == 0) { wsel = mw[p0 * TA + t + 0]; p0++; }
            else if (sel == 1) { wsel = mw[p1 * TA + t + 1]; p1++; }
            else if (sel == 2) { wsel = mw[p2 * TA + t + 2]; p2++; }
            else               { wsel = mw[p3 * TA + t + 3]; p3++; }
            idx_out[gbase + k] = ib;
            w_out[gbase + k]   = wsel;
            rsum += wsel;
            atomicAdd(&Dsum[b * NPTS + ib], 0.5f * wsel);   // incoming (transpose) half
        }
        atomicAdd(&Dsum[b * NPTS + n], 0.5f * rsum);        // outgoing half
    }
}

// ---------------------------------------------------------------------------
// Kernel: d_is = 1/sqrt(clip(D, 1e-6))
// ---------------------------------------------------------------------------
__global__ void dis_kernel(const float* __restrict__ Dsum, float* __restrict__ dis, int n) {
    int i = blockIdx.x * blockDim.x + threadIdx.x;
    if (i < n) {
        float d = fmaxf(Dsum[i], 1e-6f);
        dis[i] = 1.0f / sqrtf(d);
    }
}

// ---------------------------------------------------------------------------
// Kernel: dense fill of L — zeros, diagonal 1.0, float4 stores (256 MB write)
// ---------------------------------------------------------------------------
__global__ __launch_bounds__(256) void fill_kernel(float4* __restrict__ L4, size_t T4) {
    size_t g4     = (size_t)blockIdx.x * blockDim.x + threadIdx.x;
    size_t stride = (size_t)gridDim.x * blockDim.x;
    for (; g4 < T4; g4 += stride) {
        size_t g  = g4 << 2;
        int o     = (int)(g & (size_t)(NPTS * (size_t)NPTS - 1)); // N^2 = 2^24
        int row   = o >> 12;
        int col0  = o & (NPTS - 1);
        float4 v;
        v.x = (row == col0    ) ? 1.0f : 0.0f;
        v.y = (row == col0 + 1) ? 1.0f : 0.0f;
        v.z = (row == col0 + 2) ? 1.0f : 0.0f;
        v.w = (row == col0 + 3) ? 1.0f : 0.0f;
        L4[g4] = v;
    }
}

// ---------------------------------------------------------------------------
// Kernel: scatter sparse -0.5*w*s_n*s_j into (n,j) and (j,n).
// Self entry (j==n) gets the add twice -> exactly A[n,n]=w_self.
// ---------------------------------------------------------------------------
__global__ __launch_bounds__(256) void scatter_kernel(const int* __restrict__ idxb,
                                                      const float* __restrict__ wb,
                                                      const float* __restrict__ dis,
                                                      float* __restrict__ L) {
    int r = blockIdx.x * blockDim.x + threadIdx.x;      // 0..B*N-1
    int b = r >> 12;
    int n = r & (NPTS - 1);
    float sn = dis[r];
    const int*   ip = idxb + (size_t)r * KNN;
    const float* wp = wb  + (size_t)r * KNN;
    float* Lb = L + (size_t)b * NPTS * NPTS;
#pragma unroll
    for (int k = 0; k < KNN; ++k) {
        int j   = ip[k];
        float v = -0.5f * wp[k] * sn * dis[(b << 12) + j];
        atomicAdd(Lb + (size_t)n * NPTS + j, v);
        atomicAdd(Lb + (size_t)j * NPTS + n, v);
    }
}

// ---------------------------------------------------------------------------
extern "C" void kernel_launch(void* const* d_in, const int* in_sizes, int n_in,
                              void* d_out, int out_size, void* d_ws, size_t ws_size,
                              hipStream_t stream) {
    const float* xyz = (const float*)d_in[0];
    const int B  = in_sizes[0] / (3 * NPTS);            // 4
    const int BN = B * NPTS;                            // 16384

    // workspace layout: Dsum[BN] | dis[BN] | idx[BN*K] | w[BN*K]  (~2.25 MB)
    float* Dsum = (float*)d_ws;
    float* dis  = Dsum + BN;
    int*   idxb = (int*)(dis + BN);
    float* wb   = (float*)(idxb + (size_t)BN * KNN);
    float* L    = (float*)d_out;

    zero_kernel<<<BN / 256, 256, 0, stream>>>(Dsum, BN);
    knn_kernel<<<B * (NPTS / RPB), TA, 0, stream>>>(xyz, Dsum, idxb, wb);
    dis_kernel<<<BN / 256, 256, 0, stream>>>(Dsum, dis, BN);
    size_t T4 = (size_t)B * NPTS * NPTS / 4;
    fill_kernel<<<4096, 256, 0, stream>>>((float4*)d_out, T4);
    scatter_kernel<<<BN / 256, 256, 0, stream>>>(idxb, wb, dis, L);
}

// Round 3
// 369.603 us; speedup vs baseline: 1.4830x; 1.4830x over previous
//
#include <hip/hip_runtime.h>
#include <math.h>

// Match numpy's non-FMA evaluation of the distance formula (ranking fidelity).
#pragma clang fp contract(off)

#define NPTS 4096
#define KNN  16
#define RPBK 16     // rows per block in knn kernel (one wave per row)
#define KT   1024   // knn threads per block
#define CAP  128    // filtered-candidate list capacity per row

// ordered-uint transform: monotone map f32 -> u32 (canonicalize -0 -> +0 first)
__device__ __forceinline__ unsigned okey(float f) {
    f = f + 0.0f;
    unsigned u = __float_as_uint(f);
    return u ^ (((unsigned)((int)u >> 31)) | 0x80000000u);
}

__device__ __forceinline__ unsigned wmin32(unsigned v) {
    for (int o = 32; o > 0; o >>= 1) { unsigned w = __shfl_xor(v, o); v = w < v ? w : v; }
    return v;
}
__device__ __forceinline__ unsigned long long wmin64(unsigned long long v) {
    for (int o = 32; o > 0; o >>= 1) { unsigned long long w = __shfl_xor(v, o); v = w < v ? w : v; }
    return v;
}

// ---------------------------------------------------------------------------
__global__ void zero_kernel(float* __restrict__ p, int n) {
    int i = blockIdx.x * blockDim.x + threadIdx.x;
    if (i < n) p[i] = 0.0f;
}

// ---------------------------------------------------------------------------
// KNN via threshold-filter + exact small select. One wave per row.
// Selection key is lexicographic (okey(d2_formula), idx) == lax.top_k order.
// ---------------------------------------------------------------------------
__global__ __launch_bounds__(KT, 8) void knn_kernel(const float* __restrict__ xyz,
                                                    float* __restrict__ Dsum,
                                                    int* __restrict__ idx_out,
                                                    float* __restrict__ w_out) {
    __shared__ float4 spts[NPTS];            // 64 KB: (x,y,z,|p|^2)
    __shared__ int    lists[RPBK][CAP];      // 8 KB

    const int t    = threadIdx.x;
    const int lane = t & 63;
    const int wv   = t >> 6;                              // local row
    const int rowg = blockIdx.x * RPBK + wv;              // 0..BN-1
    const int b    = rowg >> 12;
    const float* X = xyz + (size_t)b * 3 * NPTS;

    for (int i = t; i < NPTS; i += KT) {
        float x = X[i], y = X[NPTS + i], z = X[2 * NPTS + i];
        spts[i] = make_float4(x, y, z, (x * x + y * y) + z * z);   // numpy order
    }
    __syncthreads();

    const float4 P = spts[rowg & (NPTS - 1)];

    // ---- phase 1: per-lane chunk minimum; T = 16th smallest lane-min ----
    unsigned best1 = 0xFFFFFFFFu;
    for (int i = 0; i < NPTS / 64; ++i) {
        float4 Q  = spts[i * 64 + lane];
        float dot = (P.x * Q.x + P.y * Q.y) + P.z * Q.z;           // einsum order
        float d2  = (P.w + Q.w) - 2.0f * dot;                      // (sq+sq)-2dot
        unsigned k = okey(d2);
        best1 = k < best1 ? k : best1;
    }
    unsigned cur = best1, T = 0;
    for (int r = 0; r < KNN; ++r) {
        unsigned mn = wmin32(cur);
        T = mn;
        if (cur == mn) cur = 0xFFFFFFFFu;
    }

    // ---- phase 2: filter candidates with key <= T into LDS list ----
    int cnt = 0;
    for (int i = 0; i < NPTS / 64; ++i) {
        int m = i * 64 + lane;
        float4 Q  = spts[m];
        float dot = (P.x * Q.x + P.y * Q.y) + P.z * Q.z;
        float d2  = (P.w + Q.w) - 2.0f * dot;
        bool pass = okey(d2) <= T;
        unsigned long long bal = __ballot(pass);
        if (pass) {
            int pos = cnt + __popcll(bal & ((1ull << lane) - 1ull));
            if (pos < CAP) lists[wv][pos] = m;
        }
        cnt += (int)__popcll(bal);
    }

    // ---- phase 3: exact top-16 by (key, idx) ----
    unsigned long long sel = ~0ull;
    if (cnt <= CAP) {
        unsigned long long e0 = ~0ull, e1 = ~0ull;
        if (lane < cnt) {
            int m = lists[wv][lane]; float4 Q = spts[m];
            float dot = (P.x * Q.x + P.y * Q.y) + P.z * Q.z;
            float d2  = (P.w + Q.w) - 2.0f * dot;
            e0 = ((unsigned long long)okey(d2) << 32) | (unsigned)m;
        }
        if (lane + 64 < cnt) {
            int m = lists[wv][lane + 64]; float4 Q = spts[m];
            float dot = (P.x * Q.x + P.y * Q.y) + P.z * Q.z;
            float d2  = (P.w + Q.w) - 2.0f * dot;
            e1 = ((unsigned long long)okey(d2) << 32) | (unsigned)m;
        }
        unsigned long long c = e0 < e1 ? e0 : e1;
        for (int r = 0; r < KNN; ++r) {
            unsigned long long mn = wmin64(c);
            if (c == mn) {                       // unique key -> exactly one lane
                if (e0 == mn) e0 = ~0ull; else e1 = ~0ull;
                c = e0 < e1 ? e0 : e1;
            }
            if (lane == r) sel = mn;
        }
    } else {
        // overflow fallback (astronomically rare for random data): exact 16
        // rounds of strictly-increasing wave-min over the full candidate set
        unsigned long long last = 0;
        for (int r = 0; r < KNN; ++r) {
            unsigned long long bestp = ~0ull;
            for (int i = 0; i < NPTS / 64; ++i) {
                int m = i * 64 + lane;
                float4 Q  = spts[m];
                float dot = (P.x * Q.x + P.y * Q.y) + P.z * Q.z;
                float d2  = (P.w + Q.w) - 2.0f * dot;
                unsigned long long key = ((unsigned long long)okey(d2) << 32) | (unsigned)m;
                if (key > last && key < bestp) bestp = key;
            }
            unsigned long long mn = wmin64(bestp);
            if (lane == r) sel = mn;
            last = mn;
        }
    }

    // ---- winners on lanes 0..15: exact-diff weights, outputs, degrees ----
    float wgt = 0.0f;
    if (lane < KNN) {
        int j = (int)(unsigned)(sel & 0xFFFFFFFFull);
        float4 Q = spts[j];
        float dx = P.x - Q.x, dy = P.y - Q.y, dz = P.z - Q.z;
        float dist2 = (dx * dx + dy * dy) + dz * dz;                // numpy order
        wgt = expf(-(dist2 * 0.5f));                                // == -dist2/2.0
        size_t base = (size_t)rowg * KNN + lane;
        idx_out[base] = j;
        w_out[base]   = wgt;
        atomicAdd(&Dsum[(b << 12) + j], 0.5f * wgt);                // transpose half
    }
    float rs = wgt;
    for (int o = 32; o > 0; o >>= 1) rs += __shfl_xor(rs, o);
    if (lane == 0) atomicAdd(&Dsum[rowg], 0.5f * rs);               // outgoing half
}

// ---------------------------------------------------------------------------
__global__ void dis_kernel(const float* __restrict__ Dsum, float* __restrict__ dis, int n) {
    int i = blockIdx.x * blockDim.x + threadIdx.x;
    if (i < n) dis[i] = 1.0f / sqrtf(fmaxf(Dsum[i], 1e-6f));
}

// ---------------------------------------------------------------------------
// Dense fill of L: zeros + unit diagonal, float4 stores (256 MB write)
// ---------------------------------------------------------------------------
__global__ __launch_bounds__(256) void fill_kernel(float4* __restrict__ L4, size_t T4) {
    size_t g4     = (size_t)blockIdx.x * blockDim.x + threadIdx.x;
    size_t stride = (size_t)gridDim.x * blockDim.x;
    for (; g4 < T4; g4 += stride) {
        size_t g = g4 << 2;
        int o    = (int)(g & (size_t)(NPTS * (size_t)NPTS - 1));   // N^2 = 2^24
        int row  = o >> 12;
        int col0 = o & (NPTS - 1);
        float4 v;
        v.x = (row == col0    ) ? 1.0f : 0.0f;
        v.y = (row == col0 + 1) ? 1.0f : 0.0f;
        v.z = (row == col0 + 2) ? 1.0f : 0.0f;
        v.w = (row == col0 + 3) ? 1.0f : 0.0f;
        L4[g4] = v;
    }
}

// ---------------------------------------------------------------------------
// Scatter: one thread per (row, k); adds -0.5*w*s_n*s_j to (n,j) and (j,n).
// Self entry lands twice -> exactly A[n,n] = w_self.
// ---------------------------------------------------------------------------
__global__ __launch_bounds__(256) void scatter_kernel(const int* __restrict__ idxb,
                                                      const float* __restrict__ wb,
                                                      const float* __restrict__ dis,
                                                      float* __restrict__ L) {
    int g   = blockIdx.x * 256 + threadIdx.x;     // 0..BN*K-1
    int row = g >> 4;
    int b   = row >> 12;
    int n   = row & (NPTS - 1);
    int j   = idxb[g];
    float v = -0.5f * wb[g] * dis[row] * dis[(b << 12) + j];
    float* Lb = L + (size_t)b * NPTS * NPTS;
    atomicAdd(Lb + (size_t)n * NPTS + j, v);
    atomicAdd(Lb + (size_t)j * NPTS + n, v);
}

// ---------------------------------------------------------------------------
extern "C" void kernel_launch(void* const* d_in, const int* in_sizes, int n_in,
                              void* d_out, int out_size, void* d_ws, size_t ws_size,
                              hipStream_t stream) {
    const float* xyz = (const float*)d_in[0];
    const int B  = in_sizes[0] / (3 * NPTS);            // 4
    const int BN = B * NPTS;                            // 16384

    // workspace: Dsum[BN] | dis[BN] | idx[BN*K] | w[BN*K]  (~2.25 MB)
    float* Dsum = (float*)d_ws;
    float* dis  = Dsum + BN;
    int*   idxb = (int*)(dis + BN);
    float* wb   = (float*)(idxb + (size_t)BN * KNN);
    float* L    = (float*)d_out;

    zero_kernel<<<BN / 256, 256, 0, stream>>>(Dsum, BN);
    knn_kernel<<<BN / RPBK, KT, 0, stream>>>(xyz, Dsum, idxb, wb);
    dis_kernel<<<BN / 256, 256, 0, stream>>>(Dsum, dis, BN);
    size_t T4 = (size_t)B * NPTS * NPTS / 4;
    fill_kernel<<<8192, 256, 0, stream>>>((float4*)d_out, T4);
    scatter_kernel<<<(BN * KNN) / 256, 256, 0, stream>>>(idxb, wb, dis, L);
}